// Round 3
// baseline (211.310 us; speedup 1.0000x reference)
//
#include <hip/hip_runtime.h>
#include <cstdint>
#include <cstddef>

// TaskAlignedAssigner (YOLO) — B=32, A=8400, M=32, NC=80, TOPK=13
constexpr int BB = 32;
constexpr int AA = 8400;
constexpr int MM = 32;
constexpr int CC = 80;
constexpr int KK = 13;
constexpr double DEPS = 1e-9;   // module EPS
constexpr double CEPS = 1e-7;   // _ciou internal eps
constexpr double PI4 = 0.40528473456935108577;  // 4/pi^2

__device__ __forceinline__ double ciou_f64(
    double gx1, double gy1, double gx2, double gy2,
    double px1, double py1, double px2, double py2)
{
    const double w1 = gx2 - gx1, h1 = gy2 - gy1 + CEPS;
    const double w2 = px2 - px1, h2 = py2 - py1 + CEPS;
    const double iw = fmin(gx2, px2) - fmax(gx1, px1);
    const double ih = fmin(gy2, py2) - fmax(gy1, py1);
    const double inter = fmax(iw, 0.0) * fmax(ih, 0.0);
    const double uni = w1*h1 + w2*h2 - inter + CEPS;
    const double iou = inter / uni;
    const double cw = fmax(gx2, px2) - fmin(gx1, px1);
    const double ch = fmax(gy2, py2) - fmin(gy1, py1);
    const double c2 = cw*cw + ch*ch + CEPS;
    const double ddx = px1 + px2 - gx1 - gx2;
    const double ddy = py1 + py2 - gy1 - gy2;
    const double rho2 = (ddx*ddx + ddy*ddy) * 0.25;
    const double dat = atan(w2 / h2) - atan(w1 / h1);
    const double v = PI4 * (dat * dat);
    const double alpha = v / (v - iou + (1.0 + CEPS));
    return iou - (rho2 / c2 + v * alpha);
}

// better(v1,i1) beats (v2,i2): value desc, index asc (lax.top_k total order)
__device__ __forceinline__ bool better(double v1, int i1, double v2, int i2) {
    return v1 > v2 || (v1 == v2 && i1 < i2);
}

// ---------------------------------------------------------------------------
// KA: one thread per (b,a), loop over m. atan(w2/h2) hoisted per anchor,
// gt-side constants (incl. atan(w1/h1)) in LDS. Writes f64 align plane +
// per-anchor fine bitmask.
// ---------------------------------------------------------------------------
__global__ __launch_bounds__(256)
void ka_align(const float* __restrict__ pd_scores,
              const float* __restrict__ pd_bboxes,
              const float* __restrict__ anc,
              const int*   __restrict__ gt_labels,
              const float* __restrict__ gt_bboxes,
              const float* __restrict__ gt_mask,
              double* __restrict__ alignd,
              unsigned int* __restrict__ fine_bits)
{
    __shared__ double s_gx1[MM], s_gy1[MM], s_gx2[MM], s_gy2[MM];
    __shared__ double s_w1h1[MM], s_at1[MM];
    __shared__ int s_lab[MM];
    __shared__ unsigned int s_valid;

    const int b = blockIdx.y;
    const int a = blockIdx.x * 256 + threadIdx.x;

    if (threadIdx.x == 0) s_valid = 0;
    __syncthreads();
    if (threadIdx.x < MM) {
        const int m = threadIdx.x;
        const float4 gb = reinterpret_cast<const float4*>(gt_bboxes)[b*MM + m];
        const double gx1 = gb.x, gy1 = gb.y, gx2 = gb.z, gy2 = gb.w;
        s_gx1[m] = gx1; s_gy1[m] = gy1; s_gx2[m] = gx2; s_gy2[m] = gy2;
        const double w1 = gx2 - gx1, h1 = gy2 - gy1 + CEPS;
        s_w1h1[m] = w1 * h1;
        s_at1[m]  = atan(w1 / h1);
        s_lab[m]  = gt_labels[b*MM + m];
        if (gt_mask[b*MM + m] > 0.0f) atomicOr(&s_valid, 1u << m);
    }
    __syncthreads();
    if (a >= AA) return;

    const float2 ap = reinterpret_cast<const float2*>(anc)[a];
    const double ax = ap.x, ay = ap.y;
    const float4 pb = reinterpret_cast<const float4*>(pd_bboxes)[(size_t)b*AA + a];
    const double px1 = pb.x, py1 = pb.y, px2 = pb.z, py2 = pb.w;
    const double w2 = px2 - px1, h2 = py2 - py1 + CEPS;
    const double at2 = atan(w2 / h2);
    const double w2h2 = w2 * h2;
    const float* srow = pd_scores + ((size_t)b*AA + a) * CC;
    const unsigned int vmask = s_valid;
    const size_t obase = (size_t)b * MM * AA + a;
    unsigned int fb = 0;

    #pragma unroll 4
    for (int m = 0; m < MM; ++m) {
        const double gx1 = s_gx1[m], gy1 = s_gy1[m];
        const double gx2 = s_gx2[m], gy2 = s_gy2[m];
        const double mind = fmin(fmin(ax - gx1, ay - gy1),
                                 fmin(gx2 - ax, gy2 - ay));
        const bool fine = (mind > DEPS) && ((vmask >> m) & 1u);

        const double iw = fmin(gx2, px2) - fmax(gx1, px1);
        const double ih = fmin(gy2, py2) - fmax(gy1, py1);
        const double inter = fmax(iw, 0.0) * fmax(ih, 0.0);
        const double uni = s_w1h1[m] + w2h2 - inter + CEPS;
        const double iou = inter / uni;
        const double cw = fmax(gx2, px2) - fmin(gx1, px1);
        const double ch = fmax(gy2, py2) - fmin(gy1, py1);
        const double c2 = cw*cw + ch*ch + CEPS;
        const double ddx = px1 + px2 - gx1 - gx2;
        const double ddy = py1 + py2 - gy1 - gy2;
        const double rho2 = (ddx*ddx + ddy*ddy) * 0.25;
        const double dat = at2 - s_at1[m];
        const double v = PI4 * (dat * dat);
        const double alpha = v / (v - iou + (1.0 + CEPS));
        const double ciou = iou - (rho2 / c2 + v * alpha);

        const double iouc = fine ? fmax(ciou, 0.0) : 0.0;
        const double cls  = fine ? (double)srow[s_lab[m]] : 0.0;
        const double i2 = iouc * iouc;
        alignd[obase + (size_t)m * AA] = cls * (i2 * i2 * i2);
        if (fine) fb |= 1u << m;
    }
    fine_bits[(size_t)b*AA + a] = fb;
}

// ---------------------------------------------------------------------------
// KT: one WAVE per (b,m). Single streaming pass builds per-lane sorted
// top-13 in registers (static indices only), then 13 shuffle-merge rounds.
// No LDS, no __syncthreads.
// ---------------------------------------------------------------------------
__global__ __launch_bounds__(256)
void kt_topk(const double* __restrict__ alignd,
             const unsigned int* __restrict__ fine_bits,
             const float* __restrict__ gt_mask,
             unsigned int* __restrict__ bits)
{
    const int bm = blockIdx.x * 4 + (threadIdx.x >> 6);
    const int lane = threadIdx.x & 63;
    if (gt_mask[bm] <= 0.0f) return;   // wave-uniform
    const int b = bm / MM, m = bm % MM;

    const double* __restrict__ row = alignd + (size_t)bm * AA;

    double tv[KK]; int ti[KK];
    #pragma unroll
    for (int s = 0; s < KK; ++s) { tv[s] = -1.0; ti[s] = 0x7fffffff; }

    // streaming pass: lane reads a = j*64 + lane (coalesced f64)
    for (int j = 0; j < (AA + 63) / 64; ++j) {
        const int a = j * 64 + lane;
        const double v = (a < AA) ? row[a] : -1.0;
        if (better(v, a, tv[KK-1], ti[KK-1])) {
            tv[KK-1] = v; ti[KK-1] = a;
            #pragma unroll
            for (int s = KK - 1; s > 0; --s) {
                if (better(tv[s], ti[s], tv[s-1], ti[s-1])) {
                    const double tmpv = tv[s]; tv[s] = tv[s-1]; tv[s-1] = tmpv;
                    const int tmpi = ti[s]; ti[s] = ti[s-1]; ti[s-1] = tmpi;
                }
            }
        }
    }

    // 13 merge rounds across the wave
    unsigned int cons = 0;   // consumed-slot mask (per lane)
    for (int k = 0; k < KK; ++k) {
        // local best unconsumed (static scan)
        double bv = -1.0; int bi = 0x7fffffff; int bs = -1;
        #pragma unroll
        for (int s = 0; s < KK; ++s) {
            if (!((cons >> s) & 1u) && better(tv[s], ti[s], bv, bi)) {
                bv = tv[s]; bi = ti[s]; bs = s;
            }
        }
        // wave reduce (max value, min index)
        double gv = bv; int gi = bi;
        #pragma unroll
        for (int off = 32; off > 0; off >>= 1) {
            const double ov = __shfl_down(gv, off);
            const int    oi = __shfl_down(gi, off);
            if (better(ov, oi, gv, gi)) { gv = ov; gi = oi; }
        }
        gv = __shfl(gv, 0); gi = __shfl(gi, 0);
        // owner lane consumes + writes
        if (gi == bi && bs >= 0) {
            cons |= 1u << bs;
            if (fine_bits[b*AA + gi] & (1u << m))
                atomicOr(&bits[b*AA + gi], 1u << m);
        }
    }
}

// ---------------------------------------------------------------------------
// KB: per (b,a) — resolve multi-assignment (argmax_m of f64-recomputed masked
// iou, first-tie), write labels/bboxes/tgt/fg, and fuse pos_align/pos_ov via
// float-as-uint atomicMax (all values >= 0).
// ---------------------------------------------------------------------------
__global__ __launch_bounds__(256)
void kb_resolve(const int*   __restrict__ gt_labels,
                const float* __restrict__ gt_bboxes,
                const float* __restrict__ pd_bboxes,
                const unsigned int* __restrict__ fine_bits,
                const double* __restrict__ alignd,
                unsigned int* __restrict__ bits,
                float* __restrict__ out_labels,
                float* __restrict__ out_bboxes,
                float* __restrict__ out_tgt,
                float* __restrict__ out_fg,
                unsigned int* __restrict__ posal_u,
                unsigned int* __restrict__ posov_u)
{
    const int idx = blockIdx.x * 256 + threadIdx.x;
    if (idx >= BB * AA) return;
    const int b = idx / AA, a = idx - b * AA;

    unsigned int bt = bits[idx];
    const int cnt = __popc(bt);
    int tgt = 0; float fg = 0.0f;

    if (cnt > 0) {
        fg = 1.0f;
        const float4 pb = reinterpret_cast<const float4*>(pd_bboxes)[(size_t)b*AA + a];
        const unsigned int fb = fine_bits[idx];
        double iou_t = 0.0;
        if (cnt > 1) {
            double bestv = -1.0; int bmx = 0;
            for (int m = 0; m < MM; ++m) {
                double v = 0.0;
                if ((fb >> m) & 1u) {
                    const float4 gb = reinterpret_cast<const float4*>(gt_bboxes)[b*MM + m];
                    v = fmax(ciou_f64(gb.x, gb.y, gb.z, gb.w, pb.x, pb.y, pb.z, pb.w), 0.0);
                }
                if (v > bestv) { bestv = v; bmx = m; }   // ties -> first m
            }
            tgt = bmx; bt = 1u << bmx; iou_t = bestv;
        } else {
            tgt = __ffs(bt) - 1;
            if ((fb >> tgt) & 1u) {
                const float4 gb = reinterpret_cast<const float4*>(gt_bboxes)[b*MM + tgt];
                iou_t = fmax(ciou_f64(gb.x, gb.y, gb.z, gb.w, pb.x, pb.y, pb.z, pb.w), 0.0);
            }
        }
        const float al = (float)alignd[((size_t)b*MM + tgt)*AA + a];
        atomicMax(&posal_u[b*MM + tgt], __float_as_uint(al));
        atomicMax(&posov_u[b*MM + tgt], __float_as_uint((float)iou_t));
    }
    bits[idx] = bt;

    int lab = gt_labels[b*MM + tgt];
    if (lab < 0) lab = 0;
    out_labels[idx] = (float)lab;
    reinterpret_cast<float4*>(out_bboxes)[idx] =
        reinterpret_cast<const float4*>(gt_bboxes)[b*MM + tgt];
    out_tgt[idx] = (float)tgt;
    out_fg[idx]  = fg;
}

// ---------------------------------------------------------------------------
// KD1: per (b,a) — norm (final mask has <=1 bit set).
// ---------------------------------------------------------------------------
__global__ __launch_bounds__(256)
void kd1_norm(const unsigned int* __restrict__ bits,
              const double* __restrict__ alignd,
              const unsigned int* __restrict__ posal_u,
              const unsigned int* __restrict__ posov_u,
              float* __restrict__ ws_norm)
{
    const int idx = blockIdx.x * 256 + threadIdx.x;
    if (idx >= BB * AA) return;
    const int b = idx / AA, a = idx - b * AA;
    const unsigned int bt = bits[idx];
    double nv = 0.0;
    if (bt) {
        const int m = __ffs(bt) - 1;
        nv = alignd[((size_t)b*MM + m)*AA + a]
           * (double)__uint_as_float(posov_u[b*MM + m])
           / ((double)__uint_as_float(posal_u[b*MM + m]) + DEPS);
    }
    ws_norm[idx] = (float)nv;
}

// ---------------------------------------------------------------------------
// KD2: float4 per thread over target_scores (B*A*NC).
// ---------------------------------------------------------------------------
__global__ __launch_bounds__(256)
void kd2_scores(const float* __restrict__ out_labels,
                const float* __restrict__ out_fg,
                const float* __restrict__ ws_norm,
                float* __restrict__ out_scores)
{
    const int i = blockIdx.x * 256 + threadIdx.x;
    if (i >= BB * AA * (CC/4)) return;
    const int cell = i / (CC/4);
    const int q = (i - cell * (CC/4)) * 4;
    float4 r = make_float4(0.f, 0.f, 0.f, 0.f);
    if (out_fg[cell] > 0.0f) {
        const int lab = (int)out_labels[cell];
        if (lab >= q && lab < q + 4) {
            const float n = ws_norm[cell];
            if (lab == q)     r.x = n;
            if (lab == q + 1) r.y = n;
            if (lab == q + 2) r.z = n;
            if (lab == q + 3) r.w = n;
        }
    }
    reinterpret_cast<float4*>(out_scores)[i] = r;
}

// ---------------------------------------------------------------------------
extern "C" void kernel_launch(void* const* d_in, const int* in_sizes, int n_in,
                              void* d_out, int out_size, void* d_ws, size_t ws_size,
                              hipStream_t stream)
{
    const float* pd_scores = (const float*)d_in[0];
    const float* pd_bboxes = (const float*)d_in[1];
    const float* anc       = (const float*)d_in[2];
    const int*   gt_labels = (const int*)d_in[3];
    const float* gt_bboxes = (const float*)d_in[4];
    const float* gt_mask   = (const float*)d_in[5];

    char* ws = (char*)d_ws;
    double* alignd = (double*)ws;               ws += (size_t)BB*MM*AA*8;   // 68.8 MB
    unsigned int* fine_bits = (unsigned int*)ws; ws += (size_t)BB*AA*4;     // 1.07 MB
    unsigned int* bits = (unsigned int*)ws;      ws += (size_t)BB*AA*4;     // 1.07 MB
    unsigned int* posal_u = (unsigned int*)ws;   ws += (size_t)BB*MM*4;
    unsigned int* posov_u = (unsigned int*)ws;   ws += (size_t)BB*MM*4;
    float* ws_norm = (float*)ws;                 ws += (size_t)BB*AA*4;

    float* out = (float*)d_out;
    float* out_labels = out;                       // B*A
    float* out_bboxes = out + (size_t)BB*AA;       // B*A*4
    float* out_scores = out + (size_t)BB*AA*5;     // B*A*NC
    float* out_tgt    = out + (size_t)BB*AA*(5+CC);
    float* out_fg     = out + (size_t)BB*AA*(6+CC);

    // bits + posal + posov are contiguous -> one async memset
    hipMemsetAsync(bits, 0, (size_t)BB*AA*4 + (size_t)BB*MM*8, stream);

    dim3 ga((AA + 255)/256, BB);
    ka_align<<<ga, 256, 0, stream>>>(pd_scores, pd_bboxes, anc, gt_labels,
                                     gt_bboxes, gt_mask, alignd, fine_bits);
    kt_topk<<<BB*MM/4, 256, 0, stream>>>(alignd, fine_bits, gt_mask, bits);
    kb_resolve<<<(BB*AA + 255)/256, 256, 0, stream>>>(gt_labels, gt_bboxes, pd_bboxes,
                                                      fine_bits, alignd, bits,
                                                      out_labels, out_bboxes,
                                                      out_tgt, out_fg,
                                                      posal_u, posov_u);
    kd1_norm<<<(BB*AA + 255)/256, 256, 0, stream>>>(bits, alignd, posal_u,
                                                    posov_u, ws_norm);
    kd2_scores<<<(BB*AA*(CC/4) + 255)/256, 256, 0, stream>>>(out_labels, out_fg,
                                                             ws_norm, out_scores);
}